// Round 9
// baseline (375.958 us; speedup 1.0000x reference)
//
#include <hip/hip_runtime.h>

typedef __attribute__((ext_vector_type(8))) __bf16 bf16x8;
typedef __attribute__((ext_vector_type(8))) unsigned short ushort8v;
typedef __attribute__((ext_vector_type(4))) float f32x4;
typedef __attribute__((ext_vector_type(4))) unsigned int u32x4;

__device__ __forceinline__ unsigned short f2bf(float f) {
  return __builtin_bit_cast(unsigned short, (__bf16)f);
}
__device__ __forceinline__ unsigned int pk2(float a, float b) {
  return (unsigned int)f2bf(a) | ((unsigned int)f2bf(b) << 16);
}

// C-frag pair -> A/B-operand frag (the r5/r6/r7 hardware-verified shuffle).
// Input: cA holds k-local 0..15 at (l4*4+rr), cB holds k-local 16..31; the surviving
// (M/N) index is in l15 on both sides. Output: lane(l4,l15) holds k = l4*8+j, j=0..7.
__device__ __forceinline__ bf16x8 conv_pair(f32x4 cA, f32x4 cB, int lane) {
  unsigned pA0 = pk2(cA[0], cA[1]);
  unsigned pA1 = pk2(cA[2], cA[3]);
  unsigned pB0 = pk2(cB[0], cB[1]);
  unsigned pB1 = pk2(cB[2], cB[3]);
  const int srcA = (lane & 15) + ((lane & 16) << 1);  // l15 + 32*(l4&1)
  const int srcB = srcA + 16;
  const bool hi = (lane & 32) != 0;                   // l4 >= 2 -> take cB-halves
  unsigned d0a = __shfl((int)pA0, srcA, 64), d0b = __shfl((int)pB0, srcA, 64);
  unsigned d1a = __shfl((int)pA1, srcA, 64), d1b = __shfl((int)pB1, srcA, 64);
  unsigned d2a = __shfl((int)pA0, srcB, 64), d2b = __shfl((int)pB0, srcB, 64);
  unsigned d3a = __shfl((int)pA1, srcB, 64), d3b = __shfl((int)pB1, srcB, 64);
  u32x4 dd;
  dd[0] = hi ? d0b : d0a; dd[1] = hi ? d1b : d1a;
  dd[2] = hi ? d2b : d2a; dd[3] = hi ? d3b : d3a;
  return __builtin_bit_cast(bf16x8, dd);
}

// Pack W{q,k,v} into MFMA operand-fragment order:
// frag (m3, t, kk): lane L holds 8 bf16 of W[t*16 + (L&15)][kk*32 + (L>>4)*8 + j].
// (For Wq/Wk this is the A-operand of the SWAPPED projection Qt = Wq*A^T (M=e);
//  for Wv it is the plain B-operand (N=m). Same layout either way.)
__global__ void prep_w(const float* __restrict__ Wq, const float* __restrict__ Wk,
                       const float* __restrict__ Wv, unsigned short* __restrict__ ws) {
  int i = blockIdx.x * 256 + threadIdx.x;
  if (i >= 3 * 16384) return;
  int m3 = i >> 14;
  int rem = i & 16383;
  int j = rem & 7;
  int ln = (rem >> 3) & 63;
  int kk = (rem >> 9) & 3;
  int t = rem >> 11;
  int e = t * 16 + (ln & 15);
  int d = kk * 32 + (ln >> 4) * 8 + j;
  const float* W = (m3 == 0) ? Wq : (m3 == 1 ? Wk : Wv);
  ws[i] = f2bf(W[e * 128 + d]);
}

// ONE WAVE = ONE BATCH ROW. Zero LDS, zero barriers. All inter-phase handoffs are
// in-register conv_pair shuffles, enabled by choosing each GEMM's operand order so
// the surviving index lands in l15:
//   Qt[e][l] = mfma(Wq_frag, A_frag)  -> C: l in l15, e in (l4,rr) -> conv -> Qf (k=e)
//   Kt[e][j] likewise -> Kf;  St[j][l] = mfma(Kf, Qf) -> C: l in l15, j in (l4,rr)
//   rowsum over j = in-lane + 2 shfl_xor;  S' packed RAW (deferred nv, r5-verified)
//   V[i][m] = mfma(A_frag, Wv_frag) -> C: m in l15, i in (l4,rr) -> conv -> Vf (k=i)
//   P[m][l] = mfma(Vf, S'f) -> C: l in l15, m in (l4,rr) -> nv[lt]*acc + x -> out
__global__ __launch_bounds__(256) void fused_attn(
    const float* __restrict__ x, const unsigned short* __restrict__ wsW,
    const float* __restrict__ bq, const float* __restrict__ bk, const float* __restrict__ bv,
    const float* __restrict__ ln_w, const float* __restrict__ ln_b,
    float* __restrict__ out) {
  const int tid = threadIdx.x;
  const int lane = tid & 63;
  const int l15 = lane & 15;
  const int l4 = lane >> 4;
  const int row = blockIdx.x * 4 + (tid >> 6);   // 0..8191
  const size_t bofs = (size_t)row * 8192;

  // ---- x in fragment order (single pass): lane holds x[it*16+l15][kk*32+l4*8 ..+8] ----
  f32x4 xa[16][2];
#pragma unroll
  for (int it = 0; it < 4; ++it)
#pragma unroll
    for (int kk = 0; kk < 4; ++kk) {
      const float* p = x + bofs + (size_t)(it * 16 + l15) * 128 + kk * 32 + l4 * 8;
      xa[it * 4 + kk][0] = *(const f32x4*)p;
      xa[it * 4 + kk][1] = *(const f32x4*)(p + 4);
    }

  // ---- LayerNorm: pure in-wave reduce (each lane owns 128 of the 8192) ----
  float s1 = 0.f, s2 = 0.f;
#pragma unroll
  for (int f = 0; f < 16; ++f)
#pragma unroll
    for (int q = 0; q < 2; ++q)
#pragma unroll
      for (int c = 0; c < 4; ++c) {
        float v = xa[f][q][c];
        s1 += v; s2 += v * v;
      }
#pragma unroll
  for (int off = 32; off > 0; off >>= 1) {
    s1 += __shfl_xor(s1, off, 64);
    s2 += __shfl_xor(s2, off, 64);
  }
  const float mu = s1 * (1.f / 8192.f);
  const float rstd = rsqrtf(s2 * (1.f / 8192.f) - mu * mu + 1e-5f);

  // ---- pack A-frags (B-operand layout: part-row in l15, k=d in l4*8+j) ----
  bf16x8 af[16];
#pragma unroll
  for (int it = 0; it < 4; ++it)
#pragma unroll
    for (int kk = 0; kk < 4; ++kk) {
      const int f = it * 4 + kk;
      const float* pw = ln_w + (size_t)(it * 16 + l15) * 128 + kk * 32 + l4 * 8;
      const float* pb = ln_b + (size_t)(it * 16 + l15) * 128 + kk * 32 + l4 * 8;
      f32x4 w0 = *(const f32x4*)pw, w1 = *(const f32x4*)(pw + 4);
      f32x4 b0 = *(const f32x4*)pb, b1 = *(const f32x4*)(pb + 4);
      ushort8v t;
#pragma unroll
      for (int c = 0; c < 4; ++c) {
        t[c]     = f2bf((xa[f][0][c] - mu) * rstd * w0[c] + b0[c]);
        t[4 + c] = f2bf((xa[f][1][c] - mu) * rstd * w1[c] + b1[c]);
      }
      af[f] = __builtin_bit_cast(bf16x8, t);
    }
  // xa dead.

  // ---- S phase: stream e in chunks of 32; St[j][l] accumulates in registers ----
  f32x4 sacc[4][4];   // [jt][lt]
#pragma unroll
  for (int jt = 0; jt < 4; ++jt)
#pragma unroll
    for (int lt = 0; lt < 4; ++lt)
      sacc[jt][lt] = (f32x4){0.f, 0.f, 0.f, 0.f};

#pragma unroll 1
  for (int ec = 0; ec < 4; ++ec) {
    bf16x8 qf[4], kf[4];
    {  // Q-slice: Qt[e][l] for e in [32ec, 32ec+32)
      bf16x8 w0[4], w1[4];
#pragma unroll
      for (int kk = 0; kk < 4; ++kk) {
        w0[kk] = *(const bf16x8*)(wsW + (((2 * ec) * 4 + kk) * 64 + lane) * 8);
        w1[kk] = *(const bf16x8*)(wsW + (((2 * ec + 1) * 4 + kk) * 64 + lane) * 8);
      }
      f32x4 bqa = *(const f32x4*)(bq + ec * 32 + l4 * 4);
      f32x4 bqb = *(const f32x4*)(bq + ec * 32 + 16 + l4 * 4);
#pragma unroll
      for (int lt = 0; lt < 4; ++lt) {
        f32x4 c0 = {0.f, 0.f, 0.f, 0.f}, c1 = {0.f, 0.f, 0.f, 0.f};
#pragma unroll
        for (int kk = 0; kk < 4; ++kk) {
          c0 = __builtin_amdgcn_mfma_f32_16x16x32_bf16(w0[kk], af[lt * 4 + kk], c0, 0, 0, 0);
          c1 = __builtin_amdgcn_mfma_f32_16x16x32_bf16(w1[kk], af[lt * 4 + kk], c1, 0, 0, 0);
        }
        f32x4 y0, y1;
#pragma unroll
        for (int rr = 0; rr < 4; ++rr) {
          float z0 = c0[rr] + bqa[rr]; y0[rr] = z0 > 0.f ? z0 + 1.f : __expf(z0);
          float z1 = c1[rr] + bqb[rr]; y1[rr] = z1 > 0.f ? z1 + 1.f : __expf(z1);
        }
        qf[lt] = conv_pair(y0, y1, lane);
      }
    }
    {  // K-slice (identical, Wk table + bk)
      bf16x8 w0[4], w1[4];
#pragma unroll
      for (int kk = 0; kk < 4; ++kk) {
        w0[kk] = *(const bf16x8*)(wsW + 16384 + (((2 * ec) * 4 + kk) * 64 + lane) * 8);
        w1[kk] = *(const bf16x8*)(wsW + 16384 + (((2 * ec + 1) * 4 + kk) * 64 + lane) * 8);
      }
      f32x4 bka = *(const f32x4*)(bk + ec * 32 + l4 * 4);
      f32x4 bkb = *(const f32x4*)(bk + ec * 32 + 16 + l4 * 4);
#pragma unroll
      for (int jt = 0; jt < 4; ++jt) {
        f32x4 c0 = {0.f, 0.f, 0.f, 0.f}, c1 = {0.f, 0.f, 0.f, 0.f};
#pragma unroll
        for (int kk = 0; kk < 4; ++kk) {
          c0 = __builtin_amdgcn_mfma_f32_16x16x32_bf16(w0[kk], af[jt * 4 + kk], c0, 0, 0, 0);
          c1 = __builtin_amdgcn_mfma_f32_16x16x32_bf16(w1[kk], af[jt * 4 + kk], c1, 0, 0, 0);
        }
        f32x4 y0, y1;
#pragma unroll
        for (int rr = 0; rr < 4; ++rr) {
          float z0 = c0[rr] + bka[rr]; y0[rr] = z0 > 0.f ? z0 + 1.f : __expf(z0);
          float z1 = c1[rr] + bkb[rr]; y1[rr] = z1 > 0.f ? z1 + 1.f : __expf(z1);
        }
        kf[jt] = conv_pair(y0, y1, lane);
      }
    }
    // St += Kf x Qf over this 32-e chunk
#pragma unroll
    for (int jt = 0; jt < 4; ++jt)
#pragma unroll
      for (int lt = 0; lt < 4; ++lt)
        sacc[jt][lt] = __builtin_amdgcn_mfma_f32_16x16x32_bf16(kf[jt], qf[lt], sacc[jt][lt], 0, 0, 0);
  }

  // ---- rowsum over j -> nv[lt] (in-lane sums + 2 shfl_xor across l4 groups) ----
  float nv[4];
#pragma unroll
  for (int lt = 0; lt < 4; ++lt) {
    float p = 0.f;
#pragma unroll
    for (int jt = 0; jt < 4; ++jt)
#pragma unroll
      for (int rr = 0; rr < 4; ++rr) p += sacc[jt][lt][rr];
    p += __shfl_xor(p, 16, 64);
    p += __shfl_xor(p, 32, 64);
    nv[lt] = 1.f / (p + 1e-7f);
  }

  // ---- pack RAW S' (deferred normalization): B-frags col=l in l15, k=j ----
  bf16x8 sf[2][4];
#pragma unroll
  for (int kf2 = 0; kf2 < 2; ++kf2)
#pragma unroll
    for (int lt = 0; lt < 4; ++lt)
      sf[kf2][lt] = conv_pair(sacc[2 * kf2][lt], sacc[2 * kf2 + 1][lt], lane);
  // sacc dead.

  // ---- P phase: stream V per m-tile; P[m][l] = sum_i V[i][m] S'[l][i] ----
#pragma unroll 1
  for (int mt = 0; mt < 8; ++mt) {
    bf16x8 wv[4];
#pragma unroll
    for (int kk = 0; kk < 4; ++kk)
      wv[kk] = *(const bf16x8*)(wsW + 2 * 16384 + ((mt * 4 + kk) * 64 + lane) * 8);
    const float bvm = bv[mt * 16 + l15];          // V C-frag: col=m in l15
    f32x4 vc[4];
#pragma unroll
    for (int it = 0; it < 4; ++it) {
      f32x4 c = {0.f, 0.f, 0.f, 0.f};
#pragma unroll
      for (int kk = 0; kk < 4; ++kk)
        c = __builtin_amdgcn_mfma_f32_16x16x32_bf16(af[it * 4 + kk], wv[kk], c, 0, 0, 0);
#pragma unroll
      for (int rr = 0; rr < 4; ++rr) c[rr] += bvm;
      vc[it] = c;
    }
    bf16x8 vf0 = conv_pair(vc[0], vc[1], lane);   // k=i 0..31
    bf16x8 vf1 = conv_pair(vc[2], vc[3], lane);   // k=i 32..63
#pragma unroll
    for (int lt = 0; lt < 4; ++lt) {
      f32x4 pa = {0.f, 0.f, 0.f, 0.f};
      pa = __builtin_amdgcn_mfma_f32_16x16x32_bf16(vf0, sf[0][lt], pa, 0, 0, 0);
      pa = __builtin_amdgcn_mfma_f32_16x16x32_bf16(vf1, sf[1][lt], pa, 0, 0, 0);
      const size_t idx = bofs + (size_t)(lt * 16 + l15) * 128 + mt * 16 + l4 * 4;
      f32x4 xr = *(const f32x4*)(x + idx);        // residual (L2/LLC-hot)
      f32x4 o;
#pragma unroll
      for (int rr = 0; rr < 4; ++rr) o[rr] = pa[rr] * nv[lt] + xr[rr];
      *(f32x4*)(out + idx) = o;
    }
  }
}

extern "C" void kernel_launch(void* const* d_in, const int* in_sizes, int n_in,
                              void* d_out, int out_size, void* d_ws, size_t ws_size,
                              hipStream_t stream) {
  const float* x   = (const float*)d_in[0];
  const float* Wq  = (const float*)d_in[1];
  const float* bq  = (const float*)d_in[2];
  const float* Wk  = (const float*)d_in[3];
  const float* bk  = (const float*)d_in[4];
  const float* Wv  = (const float*)d_in[5];
  const float* bv  = (const float*)d_in[6];
  const float* lnw = (const float*)d_in[7];
  const float* lnb = (const float*)d_in[8];
  unsigned short* ws = (unsigned short*)d_ws;  // 96 KB bf16 weight-fragment tables
  float* out = (float*)d_out;

  prep_w<<<192, 256, 0, stream>>>(Wq, Wk, Wv, ws);
  fused_attn<<<2048, 256, 0, stream>>>(x, ws, bq, bk, bv, lnw, lnb, out);
}

// Round 10
// 198.727 us; speedup vs baseline: 1.8918x; 1.8918x over previous
//
#include <hip/hip_runtime.h>

typedef __attribute__((ext_vector_type(8))) __bf16 bf16x8;
typedef __attribute__((ext_vector_type(8))) unsigned short ushort8v;
typedef __attribute__((ext_vector_type(4))) float f32x4;

__device__ __forceinline__ unsigned short f2bf(float f) {
  return __builtin_bit_cast(unsigned short, (__bf16)f);
}

// Swizzled byte offsets (XOR row-bits into the 16B-slot index -> no bank conflicts, G4)
__device__ __forceinline__ int qoff(int row, int colb) {  // 256B rows (A/Q/K[64][128] bf16)
  return row * 256 + (colb ^ ((row & 7) << 4));
}
__device__ __forceinline__ int toff(int row, int colb) {  // 128B rows (VT[128][64], S[64][64] bf16)
  return row * 128 + (colb ^ ((row & 7) << 4));
}

// Barrier that does NOT drain vmcnt: LDS-ordering only (m201-verified pattern).
__device__ __forceinline__ void bar_lds() {
  asm volatile("s_waitcnt lgkmcnt(0)" ::: "memory");
  __builtin_amdgcn_s_barrier();
}

__global__ void prep_w(const float* __restrict__ Wq, const float* __restrict__ Wk,
                       const float* __restrict__ Wv, unsigned short* __restrict__ ws) {
  int i = blockIdx.x * 256 + threadIdx.x;
  if (i >= 3 * 16384) return;
  const float* s = (i < 16384) ? Wq : (i < 32768 ? Wk : Wv);
  ws[i] = f2bf(s[i & 16383]);
}

// 8 rows/block, grid 1024 (4 blocks/CU queued, 2 resident), r8's verified 3-barrier
// pipelined row body unchanged:
// (1) LN stats pipelined one row ahead (reduce runs under row r's S-MFMAs).
// (2) Raw S + deferred normalization (nv applied post-P-MFMA).
// Grid-shape change only: 2x per-block work amortizes prologue/heads better and gives
// the dispatcher long-lived partner blocks so 2-block/CU residency actually holds
// (8192-block runs measured 43% occupancy vs 22% for 2048-block runs at the SAME
// resources -- this round A/Bs the residency lever with the champion body).
__global__ __launch_bounds__(512, 2) void fused_attn(
    const float* __restrict__ x, const unsigned short* __restrict__ wsW,
    const float* __restrict__ bq, const float* __restrict__ bk, const float* __restrict__ bv,
    const float* __restrict__ ln_w, const float* __restrict__ ln_b,
    float* __restrict__ out) {
  __shared__ __align__(16) unsigned char smem[74368];
  unsigned char* sA  = smem;            // A[64][128] bf16 (qoff)
  unsigned char* sQ  = smem + 16384;    // Q[64][128] bf16 (qoff)
  unsigned char* sK  = smem + 32768;    // K[64][128] bf16 (qoff)
  unsigned char* sVT = smem + 49152;    // V^T[128][64] bf16 (toff)
  unsigned char* sS  = smem + 65536;    // S_raw[64][64] bf16 (toff)
  float* redS  = (float*)(smem + 73728);   // [2][16] double-buffered LN partials
  float* pPart = (float*)(smem + 73856);   // [8][16] S rowsum partials

  const int tid = threadIdx.x;
  const int lane = tid & 63;
  const int w = tid >> 6;            // wave 0..7
  const int l15 = lane & 15;
  const int l4 = lane >> 4;          // 0..3
  const size_t base = (size_t)blockIdx.x * (8 * 8192);

  // ---- persistent: weights (24 VGPR) + biases + ln slices (32 VGPR) ----
  bf16x8 wf[3][4];
  const int col = (w << 4) + l15;
#pragma unroll
  for (int m = 0; m < 3; ++m) {
    const unsigned short* wp = wsW + m * 16384 + col * 128 + (l4 << 3);
#pragma unroll
    for (int kk = 0; kk < 4; ++kk)
      wf[m][kk] = *(const bf16x8*)(wp + kk * 32);
  }
  const float biasQ = bq[col], biasK = bk[col], biasV = bv[col];

  const int row_x = tid >> 3;        // 0..63
  const int c0 = (tid & 7) << 4;     // 0..112
  float lw[16], lb[16];
  {
    const float* pw = ln_w + row_x * 128 + c0;
    const float* pb = ln_b + row_x * 128 + c0;
#pragma unroll
    for (int i = 0; i < 4; ++i) {
      float4 a = *(const float4*)(pw + i * 4);
      lw[i*4+0]=a.x; lw[i*4+1]=a.y; lw[i*4+2]=a.z; lw[i*4+3]=a.w;
      float4 b = *(const float4*)(pb + i * 4);
      lb[i*4+0]=b.x; lb[i*4+1]=b.y; lb[i*4+2]=b.z; lb[i*4+3]=b.w;
    }
  }

  // ---- prologue: row 0's x + its LN reduce (paid once per 8 rows) ----
  float xv[16];
  {
    const float* xp = x + base + (size_t)row_x * 128 + c0;
#pragma unroll
    for (int i = 0; i < 4; ++i) {
      float4 a = *(const float4*)(xp + i * 4);
      xv[i*4+0]=a.x; xv[i*4+1]=a.y; xv[i*4+2]=a.z; xv[i*4+3]=a.w;
    }
  }
  {
    float s1 = 0.f, s2 = 0.f;
#pragma unroll
    for (int i = 0; i < 16; ++i) { s1 += xv[i]; s2 += xv[i] * xv[i]; }
#pragma unroll
    for (int off = 32; off > 0; off >>= 1) {
      s1 += __shfl_xor(s1, off, 64);
      s2 += __shfl_xor(s2, off, 64);
    }
    if (lane == 0) { redS[w] = s1; redS[8 + w] = s2; }
  }
  bar_lds();  // prologue: redS buf0 visible

#pragma unroll 1
  for (int r = 0; r < 8; ++r) {
    const size_t bofs = base + (size_t)r * 8192;

    // ---- head: stats ready immediately (pipelined); pack A; issue next-row x ----
    const float* rb = redS + (r & 1) * 16;
    float t1 = 0.f, t2 = 0.f;
#pragma unroll
    for (int p = 0; p < 8; ++p) { t1 += rb[p]; t2 += rb[8 + p]; }
    const float mu = t1 * (1.f / 8192.f);
    const float rstd = rsqrtf(t2 * (1.f / 8192.f) - mu * mu + 1e-5f);
#pragma unroll
    for (int h = 0; h < 2; ++h) {
      ushort8v t;
#pragma unroll
      for (int j = 0; j < 8; ++j)
        t[j] = f2bf((xv[h*8+j] - mu) * rstd * lw[h*8+j] + lb[h*8+j]);
      *(ushort8v*)(sA + qoff(row_x, (c0 << 1) + h * 16)) = t;
    }
    if (r < 7) {  // refill xv: in flight across GEMM1; reduced during P2
      const float* xp = x + bofs + 8192 + (size_t)row_x * 128 + c0;
#pragma unroll
      for (int i = 0; i < 4; ++i) {
        float4 a = *(const float4*)(xp + i * 4);
        xv[i*4+0]=a.x; xv[i*4+1]=a.y; xv[i*4+2]=a.z; xv[i*4+3]=a.w;
      }
    }
    bar_lds();  // B_A: A visible

    // ---- P1: GEMM1 (col-split): Q,K,V from reg-weights ----
#pragma unroll
    for (int mt = 0; mt < 4; ++mt) {
      bf16x8 aq[4];
#pragma unroll
      for (int kk = 0; kk < 4; ++kk)
        aq[kk] = *(const bf16x8*)(sA + qoff(mt * 16 + l15, kk * 64 + (l4 << 4)));
      const int i0m = mt * 16 + (l4 << 2);
      f32x4 aQ = {0,0,0,0}, aK = {0,0,0,0}, aV = {0,0,0,0};
#pragma unroll
      for (int kk = 0; kk < 4; ++kk) {
        aQ = __builtin_amdgcn_mfma_f32_16x16x32_bf16(aq[kk], wf[0][kk], aQ, 0, 0, 0);
        aK = __builtin_amdgcn_mfma_f32_16x16x32_bf16(aq[kk], wf[1][kk], aK, 0, 0, 0);
        aV = __builtin_amdgcn_mfma_f32_16x16x32_bf16(aq[kk], wf[2][kk], aV, 0, 0, 0);
      }
#pragma unroll
      for (int rr = 0; rr < 4; ++rr) {
        float zq = aQ[rr] + biasQ; zq = zq > 0.f ? zq + 1.f : __expf(zq);
        *(unsigned short*)(sQ + qoff(i0m + rr, col * 2)) = f2bf(zq);
        float zk = aK[rr] + biasK; zk = zk > 0.f ? zk + 1.f : __expf(zk);
        *(unsigned short*)(sK + qoff(i0m + rr, col * 2)) = f2bf(zk);
      }
      ushort4 pk;
      pk.x = f2bf(aV[0] + biasV); pk.y = f2bf(aV[1] + biasV);
      pk.z = f2bf(aV[2] + biasV); pk.w = f2bf(aV[3] + biasV);
      *(ushort4*)(sVT + toff(col, i0m * 2)) = pk;
    }
    bar_lds();  // B_QK: Q,K,VT visible; A dead

    // ---- P2: S = Q K^T (wave (rt,h)); rowsum partials; NEXT row's LN reduce; raw S ----
    const int rt = w >> 1;
    const int h = w & 1;
    const int i0s = rt * 16 + (l4 << 2);
    f32x4 xr[4];
    {
      bf16x8 aq[4];
#pragma unroll
      for (int kk = 0; kk < 4; ++kk)
        aq[kk] = *(const bf16x8*)(sQ + qoff(rt * 16 + l15, kk * 64 + (l4 << 4)));
      // residual prefetch (consumed in P4; flight covers the rest of P2 + B_S)
#pragma unroll
      for (int nt = 0; nt < 4; ++nt) {
        const int l = nt * 16 + l15;
        const int mb = (w << 4) + (l4 << 2);
        xr[nt] = *(const f32x4*)(x + bofs + (size_t)l * 128 + mb);
      }
      f32x4 accS[2];
#pragma unroll
      for (int nt = 0; nt < 2; ++nt) {
        const int ntg = h * 2 + nt;
        f32x4 acc = {0,0,0,0};
#pragma unroll
        for (int kk = 0; kk < 4; ++kk) {
          bf16x8 bk_ = *(const bf16x8*)(sK + qoff(ntg * 16 + l15, kk * 64 + (l4 << 4)));
          acc = __builtin_amdgcn_mfma_f32_16x16x32_bf16(aq[kk], bk_, acc, 0, 0, 0);
        }
        accS[nt] = acc;
      }
      // partial rowsum over this half's 32 cols (4-step shfl over l15)
      float p[4];
#pragma unroll
      for (int rr = 0; rr < 4; ++rr) p[rr] = accS[0][rr] + accS[1][rr];
#pragma unroll
      for (int off = 1; off < 16; off <<= 1) {
#pragma unroll
        for (int rr = 0; rr < 4; ++rr) p[rr] += __shfl_xor(p[rr], off, 64);
      }
      if (l15 == 0) {
#pragma unroll
        for (int rr = 0; rr < 4; ++rr)
          pPart[w * 16 + (l4 << 2) + rr] = p[rr];
      }
      // NEXT row's LN reduce (xv already refilled at head; S-MFMAs cover the chain)
      if (r < 7) {
        float n1 = 0.f, n2 = 0.f;
#pragma unroll
        for (int i = 0; i < 16; ++i) { n1 += xv[i]; n2 += xv[i] * xv[i]; }
#pragma unroll
        for (int off = 32; off > 0; off >>= 1) {
          n1 += __shfl_xor(n1, off, 64);
          n2 += __shfl_xor(n2, off, 64);
        }
        if (lane == 0) {
          float* nb = redS + ((r + 1) & 1) * 16;
          nb[w] = n1; nb[8 + w] = n2;
        }
      }
      // RAW S -> sS (toff); normalization deferred to P4
#pragma unroll
      for (int nt = 0; nt < 2; ++nt) {
        const int ntg = h * 2 + nt;
#pragma unroll
        for (int rr = 0; rr < 4; ++rr)
          *(unsigned short*)(sS + toff(i0s + rr, (ntg * 16 + l15) * 2)) = f2bf(accS[nt][rr]);
      }
    }
    bar_lds();  // B_S: S_raw + pPart (+ next redS) visible

    // ---- P4: P^T[m][l] = sum_i VT[m][i] S[l][i]; scale by nv[l]; residual; store ----
    {
      float nv[4];
#pragma unroll
      for (int nt = 0; nt < 4; ++nt)
        nv[nt] = 1.f / (pPart[nt * 32 + l15] + pPart[nt * 32 + 16 + l15] + 1e-7f);
      bf16x8 av[2];
#pragma unroll
      for (int kk = 0; kk < 2; ++kk)
        av[kk] = *(const bf16x8*)(sVT + toff((w << 4) + l15, kk * 64 + (l4 << 4)));
#pragma unroll
      for (int nt = 0; nt < 4; ++nt) {
        bf16x8 bs0 = *(const bf16x8*)(sS + toff(nt * 16 + l15, (l4 << 4)));
        bf16x8 bs1 = *(const bf16x8*)(sS + toff(nt * 16 + l15, 64 + (l4 << 4)));
        f32x4 acc = {0,0,0,0};
        acc = __builtin_amdgcn_mfma_f32_16x16x32_bf16(av[0], bs0, acc, 0, 0, 0);
        acc = __builtin_amdgcn_mfma_f32_16x16x32_bf16(av[1], bs1, acc, 0, 0, 0);
        const int l = nt * 16 + l15;
        const int mb = (w << 4) + (l4 << 2);
        const size_t idx = bofs + (size_t)l * 128 + mb;
        f32x4 o;
        o[0] = acc[0] * nv[nt] + xr[nt][0];
        o[1] = acc[1] * nv[nt] + xr[nt][1];
        o[2] = acc[2] * nv[nt] + xr[nt][2];
        o[3] = acc[3] * nv[nt] + xr[nt][3];
        *(f32x4*)(out + idx) = o;
      }
    }
    // no trailing barrier: next row's pre-B_A LDS writes (sA/redS) have all their
    // row-r readers drained by B_A's per-wave lgkmcnt(0) + barrier arrival.
  }
}

extern "C" void kernel_launch(void* const* d_in, const int* in_sizes, int n_in,
                              void* d_out, int out_size, void* d_ws, size_t ws_size,
                              hipStream_t stream) {
  const float* x   = (const float*)d_in[0];
  const float* Wq  = (const float*)d_in[1];
  const float* bq  = (const float*)d_in[2];
  const float* Wk  = (const float*)d_in[3];
  const float* bk  = (const float*)d_in[4];
  const float* Wv  = (const float*)d_in[5];
  const float* bv  = (const float*)d_in[6];
  const float* lnw = (const float*)d_in[7];
  const float* lnb = (const float*)d_in[8];
  unsigned short* ws = (unsigned short*)d_ws;  // 96 KB bf16 weights
  float* out = (float*)d_out;

  prep_w<<<192, 256, 0, stream>>>(Wq, Wk, Wv, ws);
  fused_attn<<<1024, 512, 0, stream>>>(x, ws, bq, bk, bv, lnw, lnb, out);
}

// Round 11
// 189.759 us; speedup vs baseline: 1.9812x; 1.0473x over previous
//
#include <hip/hip_runtime.h>

typedef __attribute__((ext_vector_type(8))) __bf16 bf16x8;
typedef __attribute__((ext_vector_type(8))) unsigned short ushort8v;
typedef __attribute__((ext_vector_type(4))) float f32x4;

__device__ __forceinline__ unsigned short f2bf(float f) {
  return __builtin_bit_cast(unsigned short, (__bf16)f);
}

// Swizzled byte offsets (XOR row-bits into the 16B-slot index -> no bank conflicts, G4)
__device__ __forceinline__ int qoff(int row, int colb) {  // 256B rows (A/Q/K[64][128] bf16)
  return row * 256 + (colb ^ ((row & 7) << 4));
}
__device__ __forceinline__ int toff(int row, int colb) {  // 128B rows (VT[128][64], S[64][64] bf16)
  return row * 128 + (colb ^ ((row & 7) << 4));
}

// Barrier that does NOT drain vmcnt: LDS-ordering only (m201-verified pattern).
__device__ __forceinline__ void bar_lds() {
  asm volatile("s_waitcnt lgkmcnt(0)" ::: "memory");
  __builtin_amdgcn_s_barrier();
}

__global__ void prep_w(const float* __restrict__ Wq, const float* __restrict__ Wk,
                       const float* __restrict__ Wv, unsigned short* __restrict__ ws) {
  int i = blockIdx.x * 256 + threadIdx.x;
  if (i >= 3 * 16384) return;
  const float* s = (i < 16384) ? Wq : (i < 32768 ? Wk : Wv);
  ws[i] = f2bf(s[i & 16383]);
}

// 8 rows/block, grid 1024. TWO-ROW PHASE-OVERLAPPED PIPELINE, all LDS double-buffered
// (148.6 KB -> intentionally 1 block/CU; counters show ~1 block resident at 74 KB
// anyway, so the second buffer set is free). Each barrier interval co-schedules an
// MFMA-heavy phase of row r with independent VALU/memory phases of neighboring rows:
//   IA(r): G(r) GEMM1[cur]  ||  H(r+1) stats+pack A[nxt]  ||  xr-prefetch(r-1)
//   IB(r): S(r) QK^T[cur]   ||  lnred(r+2) shfl chain     ||  P(r-1) PV+store[nxt]
// 2 lgkm-only barriers/row. Hazards: every LDS write->read / read->write pair crosses
// >=1 {lgkmcnt(0)+barrier}; buffers indexed by row parity (audited r=0,1,steady,epi).
__global__ __launch_bounds__(512, 1) void fused_attn(
    const float* __restrict__ x, const unsigned short* __restrict__ wsW,
    const float* __restrict__ bq, const float* __restrict__ bk, const float* __restrict__ bv,
    const float* __restrict__ ln_w, const float* __restrict__ ln_b,
    float* __restrict__ out) {
  __shared__ __align__(16) unsigned char smem[148608];
  // sA[p]=p*16384; sQ[p]=32768+p*16384; sK[p]=65536+p*16384; sVT[p]=98304+p*16384;
  // sS[p]=131072+p*8192; redS=[2][16]f @147456; pPart=[2][8][16]f @147584
  float* redS  = (float*)(smem + 147456);
  float* pPart = (float*)(smem + 147584);

  const int tid = threadIdx.x;
  const int lane = tid & 63;
  const int w = tid >> 6;            // wave 0..7
  const int l15 = lane & 15;
  const int l4 = lane >> 4;          // 0..3
  const size_t base = (size_t)blockIdx.x * (8 * 8192);

  // ---- persistent: weights (24 VGPR) + biases + ln slices (32 VGPR) ----
  bf16x8 wf[3][4];
  const int col = (w << 4) + l15;
#pragma unroll
  for (int m = 0; m < 3; ++m) {
    const unsigned short* wp = wsW + m * 16384 + col * 128 + (l4 << 3);
#pragma unroll
    for (int kk = 0; kk < 4; ++kk)
      wf[m][kk] = *(const bf16x8*)(wp + kk * 32);
  }
  const float biasQ = bq[col], biasK = bk[col], biasV = bv[col];

  const int row_x = tid >> 3;        // 0..63
  const int c0 = (tid & 7) << 4;     // 0..112
  float lw[16], lb[16];
  {
    const float* pw = ln_w + row_x * 128 + c0;
    const float* pb = ln_b + row_x * 128 + c0;
#pragma unroll
    for (int i = 0; i < 4; ++i) {
      float4 a = *(const float4*)(pw + i * 4);
      lw[i*4+0]=a.x; lw[i*4+1]=a.y; lw[i*4+2]=a.z; lw[i*4+3]=a.w;
      float4 b = *(const float4*)(pb + i * 4);
      lb[i*4+0]=b.x; lb[i*4+1]=b.y; lb[i*4+2]=b.z; lb[i*4+3]=b.w;
    }
  }

  // ---- prologue: row0 load+reduce; H(0); row1 load+reduce ----
  float xvC[16], xvN[16];
  {
    const float* xp = x + base + (size_t)row_x * 128 + c0;
#pragma unroll
    for (int i = 0; i < 4; ++i) {
      float4 a = *(const float4*)(xp + i * 4);
      xvC[i*4+0]=a.x; xvC[i*4+1]=a.y; xvC[i*4+2]=a.z; xvC[i*4+3]=a.w;
    }
  }
  {
    float s1 = 0.f, s2 = 0.f;
#pragma unroll
    for (int i = 0; i < 16; ++i) { s1 += xvC[i]; s2 += xvC[i] * xvC[i]; }
#pragma unroll
    for (int off = 32; off > 0; off >>= 1) {
      s1 += __shfl_xor(s1, off, 64);
      s2 += __shfl_xor(s2, off, 64);
    }
    if (lane == 0) { redS[w] = s1; redS[8 + w] = s2; }
  }
  bar_lds();  // redS[0] visible
  {
    // H(0): pack row0 -> sA[0]
    float t1 = 0.f, t2 = 0.f;
#pragma unroll
    for (int p = 0; p < 8; ++p) { t1 += redS[p]; t2 += redS[8 + p]; }
    const float mu = t1 * (1.f / 8192.f);
    const float rstd = rsqrtf(t2 * (1.f / 8192.f) - mu * mu + 1e-5f);
    unsigned char* sA0 = smem;
#pragma unroll
    for (int h = 0; h < 2; ++h) {
      ushort8v t;
#pragma unroll
      for (int j = 0; j < 8; ++j)
        t[j] = f2bf((xvC[h*8+j] - mu) * rstd * lw[h*8+j] + lb[h*8+j]);
      *(ushort8v*)(sA0 + qoff(row_x, (c0 << 1) + h * 16)) = t;
    }
    // load row1 + its reduce (exposed once per block)
    const float* xp = x + base + 8192 + (size_t)row_x * 128 + c0;
#pragma unroll
    for (int i = 0; i < 4; ++i) {
      float4 a = *(const float4*)(xp + i * 4);
      xvN[i*4+0]=a.x; xvN[i*4+1]=a.y; xvN[i*4+2]=a.z; xvN[i*4+3]=a.w;
    }
    float s1 = 0.f, s2 = 0.f;
#pragma unroll
    for (int i = 0; i < 16; ++i) { s1 += xvN[i]; s2 += xvN[i] * xvN[i]; }
#pragma unroll
    for (int off = 32; off > 0; off >>= 1) {
      s1 += __shfl_xor(s1, off, 64);
      s2 += __shfl_xor(s2, off, 64);
    }
    if (lane == 0) { redS[16 + w] = s1; redS[24 + w] = s2; }
  }
  bar_lds();  // sA[0] + redS[1] visible
#pragma unroll
  for (int i = 0; i < 16; ++i) xvC[i] = xvN[i];  // xvC = row1

#pragma unroll 1
  for (int r = 0; r < 8; ++r) {
    const int cur = r & 1, nxt = cur ^ 1;
    unsigned char* sAc  = smem + cur * 16384;
    unsigned char* sAn  = smem + nxt * 16384;
    unsigned char* sQc  = smem + 32768 + cur * 16384;
    unsigned char* sKc  = smem + 65536 + cur * 16384;
    unsigned char* sVTc = smem + 98304 + cur * 16384;
    unsigned char* sVTn = smem + 98304 + nxt * 16384;
    unsigned char* sSc  = smem + 131072 + cur * 8192;
    unsigned char* sSn  = smem + 131072 + nxt * 8192;
    float* redC = redS + cur * 16;    // lnred(r+2) target
    float* redN = redS + nxt * 16;    // H(r+1) source
    float* pPc = pPart + cur * 128;
    float* pPn = pPart + nxt * 128;
    const size_t bofs = base + (size_t)r * 8192;

    // ================= IA(r): xr(r-1) prefetch || G(r) || H(r+1) =================
    f32x4 xrP[4];
    if (r >= 1) {
      const size_t bofsP = bofs - 8192;
#pragma unroll
      for (int nt = 0; nt < 4; ++nt) {
        const int l = nt * 16 + l15;
        const int mb = (w << 4) + (l4 << 2);
        xrP[nt] = *(const f32x4*)(x + bofsP + (size_t)l * 128 + mb);
      }
    }
    // G(r): GEMM1 (col-split) from sA[cur]
#pragma unroll
    for (int mt = 0; mt < 4; ++mt) {
      bf16x8 aq[4];
#pragma unroll
      for (int kk = 0; kk < 4; ++kk)
        aq[kk] = *(const bf16x8*)(sAc + qoff(mt * 16 + l15, kk * 64 + (l4 << 4)));
      const int i0m = mt * 16 + (l4 << 2);
      f32x4 aQ = {0,0,0,0}, aK = {0,0,0,0}, aV = {0,0,0,0};
#pragma unroll
      for (int kk = 0; kk < 4; ++kk) {
        aQ = __builtin_amdgcn_mfma_f32_16x16x32_bf16(aq[kk], wf[0][kk], aQ, 0, 0, 0);
        aK = __builtin_amdgcn_mfma_f32_16x16x32_bf16(aq[kk], wf[1][kk], aK, 0, 0, 0);
        aV = __builtin_amdgcn_mfma_f32_16x16x32_bf16(aq[kk], wf[2][kk], aV, 0, 0, 0);
      }
#pragma unroll
      for (int rr = 0; rr < 4; ++rr) {
        float zq = aQ[rr] + biasQ; zq = zq > 0.f ? zq + 1.f : __expf(zq);
        *(unsigned short*)(sQc + qoff(i0m + rr, col * 2)) = f2bf(zq);
        float zk = aK[rr] + biasK; zk = zk > 0.f ? zk + 1.f : __expf(zk);
        *(unsigned short*)(sKc + qoff(i0m + rr, col * 2)) = f2bf(zk);
      }
      ushort4 pk;
      pk.x = f2bf(aV[0] + biasV); pk.y = f2bf(aV[1] + biasV);
      pk.z = f2bf(aV[2] + biasV); pk.w = f2bf(aV[3] + biasV);
      *(ushort4*)(sVTc + toff(col, i0m * 2)) = pk;
    }
    // H(r+1): stats from redS[nxt] (written in IB(r-1)/prologue); pack xvC -> sA[nxt]
    if (r < 7) {
      float t1 = 0.f, t2 = 0.f;
#pragma unroll
      for (int p = 0; p < 8; ++p) { t1 += redN[p]; t2 += redN[8 + p]; }
      const float mu = t1 * (1.f / 8192.f);
      const float rstd = rsqrtf(t2 * (1.f / 8192.f) - mu * mu + 1e-5f);
#pragma unroll
      for (int h = 0; h < 2; ++h) {
        ushort8v t;
#pragma unroll
        for (int j = 0; j < 8; ++j)
          t[j] = f2bf((xvC[h*8+j] - mu) * rstd * lw[h*8+j] + lb[h*8+j]);
        *(ushort8v*)(sAn + qoff(row_x, (c0 << 1) + h * 16)) = t;
      }
      if (r < 6) {  // issue load of row r+2 (reduced in IB(r), packed in IA(r+1))
        const float* xp = x + bofs + 2 * 8192 + (size_t)row_x * 128 + c0;
#pragma unroll
        for (int i = 0; i < 4; ++i) {
          float4 a = *(const float4*)(xp + i * 4);
          xvN[i*4+0]=a.x; xvN[i*4+1]=a.y; xvN[i*4+2]=a.z; xvN[i*4+3]=a.w;
        }
      }
    }
    bar_lds();  // end IA(r)

    // ================= IB(r): S(r) || lnred(r+2) || P(r-1) =================
    // S(r): S = Q K^T from sQ/sK[cur]; rowsum partials -> pPart[cur]; raw S -> sS[cur]
    const int rt = w >> 1;
    const int h2 = w & 1;
    const int i0s = rt * 16 + (l4 << 2);
    {
      bf16x8 aq[4];
#pragma unroll
      for (int kk = 0; kk < 4; ++kk)
        aq[kk] = *(const bf16x8*)(sQc + qoff(rt * 16 + l15, kk * 64 + (l4 << 4)));
      f32x4 accS[2];
#pragma unroll
      for (int nt = 0; nt < 2; ++nt) {
        const int ntg = h2 * 2 + nt;
        f32x4 acc = {0,0,0,0};
#pragma unroll
        for (int kk = 0; kk < 4; ++kk) {
          bf16x8 bk_ = *(const bf16x8*)(sKc + qoff(ntg * 16 + l15, kk * 64 + (l4 << 4)));
          acc = __builtin_amdgcn_mfma_f32_16x16x32_bf16(aq[kk], bk_, acc, 0, 0, 0);
        }
        accS[nt] = acc;
      }
      float p[4];
#pragma unroll
      for (int rr = 0; rr < 4; ++rr) p[rr] = accS[0][rr] + accS[1][rr];
#pragma unroll
      for (int off = 1; off < 16; off <<= 1) {
#pragma unroll
        for (int rr = 0; rr < 4; ++rr) p[rr] += __shfl_xor(p[rr], off, 64);
      }
      if (l15 == 0) {
#pragma unroll
        for (int rr = 0; rr < 4; ++rr)
          pPc[w * 16 + (l4 << 2) + rr] = p[rr];
      }
#pragma unroll
      for (int nt = 0; nt < 2; ++nt) {
        const int ntg = h2 * 2 + nt;
#pragma unroll
        for (int rr = 0; rr < 4; ++rr)
          *(unsigned short*)(sSc + toff(i0s + rr, (ntg * 16 + l15) * 2)) = f2bf(accS[nt][rr]);
      }
    }
    // lnred(r+2): reduce xvN -> redS[cur]
    if (r < 6) {
      float n1 = 0.f, n2 = 0.f;
#pragma unroll
      for (int i = 0; i < 16; ++i) { n1 += xvN[i]; n2 += xvN[i] * xvN[i]; }
#pragma unroll
      for (int off = 32; off > 0; off >>= 1) {
        n1 += __shfl_xor(n1, off, 64);
        n2 += __shfl_xor(n2, off, 64);
      }
      if (lane == 0) { redC[w] = n1; redC[8 + w] = n2; }
    }
    // P(r-1): PV + residual + store from buffers [nxt]
    if (r >= 1) {
      const size_t bofsP = bofs - 8192;
      float nv[4];
#pragma unroll
      for (int nt = 0; nt < 4; ++nt)
        nv[nt] = 1.f / (pPn[nt * 32 + l15] + pPn[nt * 32 + 16 + l15] + 1e-7f);
      bf16x8 av[2];
#pragma unroll
      for (int kk = 0; kk < 2; ++kk)
        av[kk] = *(const bf16x8*)(sVTn + toff((w << 4) + l15, kk * 64 + (l4 << 4)));
#pragma unroll
      for (int nt = 0; nt < 4; ++nt) {
        bf16x8 bs0 = *(const bf16x8*)(sSn + toff(nt * 16 + l15, (l4 << 4)));
        bf16x8 bs1 = *(const bf16x8*)(sSn + toff(nt * 16 + l15, 64 + (l4 << 4)));
        f32x4 acc = {0,0,0,0};
        acc = __builtin_amdgcn_mfma_f32_16x16x32_bf16(av[0], bs0, acc, 0, 0, 0);
        acc = __builtin_amdgcn_mfma_f32_16x16x32_bf16(av[1], bs1, acc, 0, 0, 0);
        const int l = nt * 16 + l15;
        const int mb = (w << 4) + (l4 << 2);
        const size_t idx = bofsP + (size_t)l * 128 + mb;
        f32x4 o;
        o[0] = acc[0] * nv[nt] + xrP[nt][0];
        o[1] = acc[1] * nv[nt] + xrP[nt][1];
        o[2] = acc[2] * nv[nt] + xrP[nt][2];
        o[3] = acc[3] * nv[nt] + xrP[nt][3];
        *(f32x4*)(out + idx) = o;
      }
    }
    bar_lds();  // end IB(r)

    if (r < 6) {
#pragma unroll
      for (int i = 0; i < 16; ++i) xvC[i] = xvN[i];
    }
  }

  // ================= epilogue: P(7) (buffers parity 1) =================
  {
    const size_t bofsP = base + 7 * 8192;
    unsigned char* sVT1 = smem + 98304 + 16384;
    unsigned char* sS1  = smem + 131072 + 8192;
    float* pP1 = pPart + 128;
    f32x4 xr7[4];
#pragma unroll
    for (int nt = 0; nt < 4; ++nt) {
      const int l = nt * 16 + l15;
      const int mb = (w << 4) + (l4 << 2);
      xr7[nt] = *(const f32x4*)(x + bofsP + (size_t)l * 128 + mb);
    }
    float nv[4];
#pragma unroll
    for (int nt = 0; nt < 4; ++nt)
      nv[nt] = 1.f / (pP1[nt * 32 + l15] + pP1[nt * 32 + 16 + l15] + 1e-7f);
    bf16x8 av[2];
#pragma unroll
    for (int kk = 0; kk < 2; ++kk)
      av[kk] = *(const bf16x8*)(sVT1 + toff((w << 4) + l15, kk * 64 + (l4 << 4)));
#pragma unroll
    for (int nt = 0; nt < 4; ++nt) {
      bf16x8 bs0 = *(const bf16x8*)(sS1 + toff(nt * 16 + l15, (l4 << 4)));
      bf16x8 bs1 = *(const bf16x8*)(sS1 + toff(nt * 16 + l15, 64 + (l4 << 4)));
      f32x4 acc = {0,0,0,0};
      acc = __builtin_amdgcn_mfma_f32_16x16x32_bf16(av[0], bs0, acc, 0, 0, 0);
      acc = __builtin_amdgcn_mfma_f32_16x16x32_bf16(av[1], bs1, acc, 0, 0, 0);
      const int l = nt * 16 + l15;
      const int mb = (w << 4) + (l4 << 2);
      const size_t idx = bofsP + (size_t)l * 128 + mb;
      f32x4 o;
      o[0] = acc[0] * nv[nt] + xr7[nt][0];
      o[1] = acc[1] * nv[nt] + xr7[nt][1];
      o[2] = acc[2] * nv[nt] + xr7[nt][2];
      o[3] = acc[3] * nv[nt] + xr7[nt][3];
      *(f32x4*)(out + idx) = o;
    }
  }
}

extern "C" void kernel_launch(void* const* d_in, const int* in_sizes, int n_in,
                              void* d_out, int out_size, void* d_ws, size_t ws_size,
                              hipStream_t stream) {
  const float* x   = (const float*)d_in[0];
  const float* Wq  = (const float*)d_in[1];
  const float* bq  = (const float*)d_in[2];
  const float* Wk  = (const float*)d_in[3];
  const float* bk  = (const float*)d_in[4];
  const float* Wv  = (const float*)d_in[5];
  const float* bv  = (const float*)d_in[6];
  const float* lnw = (const float*)d_in[7];
  const float* lnb = (const float*)d_in[8];
  unsigned short* ws = (unsigned short*)d_ws;  // 96 KB bf16 weights
  float* out = (float*)d_out;

  prep_w<<<192, 256, 0, stream>>>(Wq, Wk, Wv, ws);
  fused_attn<<<1024, 512, 0, stream>>>(x, ws, bq, bk, bv, lnw, lnb, out);
}